// Round 3
// baseline (147.171 us; speedup 1.0000x reference)
//
#include <hip/hip_runtime.h>

#define BB 2
#define NN 512
#define FF 128
#define HH 256
#define TI 4   // i-rows per K2 block
#define TN 2   // n-rows per K1 block

// K1: s[b,n,h] = b1[h] + sum_f x[b,n,f]*w1[h,f] ; q[b,n,h] = sum_f x[b,n,f]*w1[h,FF+f]
__global__ __launch_bounds__(256) void k1_pq(const float* __restrict__ x,
    const float* __restrict__ w1, const float* __restrict__ b1,
    float* __restrict__ s_out, float* __restrict__ q_out) {
  __shared__ __align__(16) float x_l[TN][FF];
  const int blk = blockIdx.x;
  const int b  = blk / (NN / TN);
  const int n0 = (blk % (NN / TN)) * TN;
  const int t  = threadIdx.x;

  { // stage x rows (TN*FF = 256 elements, one per thread)
    int ti = t >> 7, f = t & 127;
    x_l[ti][f] = x[(b * NN + n0 + ti) * FF + f];
  }
  __syncthreads();

  const int h = t;
  const float* wrow = w1 + h * (2 * FF);
  float accp[TN], accq[TN];
  #pragma unroll
  for (int ti = 0; ti < TN; ++ti) { accp[ti] = 0.f; accq[ti] = 0.f; }

  #pragma unroll 4
  for (int f8 = 0; f8 < FF; f8 += 8) {
    float fa[8], fb[8];
    { float4 a = *(const float4*)(wrow + f8);
      float4 c = *(const float4*)(wrow + f8 + 4);
      fa[0]=a.x; fa[1]=a.y; fa[2]=a.z; fa[3]=a.w; fa[4]=c.x; fa[5]=c.y; fa[6]=c.z; fa[7]=c.w; }
    { float4 a = *(const float4*)(wrow + FF + f8);
      float4 c = *(const float4*)(wrow + FF + f8 + 4);
      fb[0]=a.x; fb[1]=a.y; fb[2]=a.z; fb[3]=a.w; fb[4]=c.x; fb[5]=c.y; fb[6]=c.z; fb[7]=c.w; }
    #pragma unroll
    for (int k = 0; k < 8; ++k) {
      #pragma unroll
      for (int ti = 0; ti < TN; ++ti) {
        float xv = x_l[ti][f8 + k];
        accp[ti] = fmaf(xv, fa[k], accp[ti]);
        accq[ti] = fmaf(xv, fb[k], accq[ti]);
      }
    }
  }
  const float bias = b1[h];
  #pragma unroll
  for (int ti = 0; ti < TN; ++ti) {
    s_out[(b * NN + n0 + ti) * HH + h] = accp[ti] + bias;  // fold b1 into s
    q_out[(b * NN + n0 + ti) * HH + h] = accq[ti];
  }
}

// K2: e -> leaky -> mask -> softmax -> next_h, per (b, 4 i-rows)
__global__ __launch_bounds__(512) void k2_attn(const float* __restrict__ s_in,
    const float* __restrict__ q_in, const float* __restrict__ x,
    const float* __restrict__ w2, const float* __restrict__ b2,
    const int* __restrict__ adj, float* __restrict__ out) {
  __shared__ __align__(16) float s_l[TI][HH];          // 4 KB
  __shared__ __align__(16) float w2_l[HH];             // 1 KB
  __shared__ __align__(16) float e_l[TI][NN];          // 8 KB (e -> attention in place)
  __shared__ __align__(16) float part_l[2][TI][FF];    // 4 KB

  const int blk = blockIdx.x;
  const int b  = blk >> 7;          // / (NN/TI = 128)
  const int i0 = (blk & 127) * TI;
  const int t  = threadIdx.x;       // 0..511
  const int wv = t >> 6, ln = t & 63;

  for (int idx = t; idx < TI * HH; idx += 512) {
    int ti = idx >> 8, h = idx & 255;
    s_l[ti][h] = s_in[(b * NN + i0 + ti) * HH + h];
  }
  if (t < HH) w2_l[t] = w2[t];
  const float b2v = b2[0];
  __syncthreads();

  // ---- e[ti][j] for j = t ----
  {
    const int j = t;
    const float* qrow = q_in + (b * NN + j) * HH;
    float acc[TI] = {0.f, 0.f, 0.f, 0.f};
    for (int h0 = 0; h0 < HH; h0 += 4) {
      float4 q4 = *(const float4*)(qrow + h0);
      float4 w4 = *(const float4*)(&w2_l[h0]);      // broadcast LDS
      #pragma unroll
      for (int ti = 0; ti < TI; ++ti) {
        float4 s4 = *(const float4*)(&s_l[ti][h0]); // broadcast LDS
        acc[ti] = fmaf(fmaxf(s4.x + q4.x, 0.f), w4.x, acc[ti]);
        acc[ti] = fmaf(fmaxf(s4.y + q4.y, 0.f), w4.y, acc[ti]);
        acc[ti] = fmaf(fmaxf(s4.z + q4.z, 0.f), w4.z, acc[ti]);
        acc[ti] = fmaf(fmaxf(s4.w + q4.w, 0.f), w4.w, acc[ti]);
      }
    }
    #pragma unroll
    for (int ti = 0; ti < TI; ++ti) {
      float e = acc[ti] + b2v;
      e = e > 0.f ? e : 0.04f * e;                       // leaky relu
      int av = adj[(b * NN + i0 + ti) * NN + j];
      e_l[ti][j] = (av > 0) ? e : -9.0e15f;              // mask
    }
  }
  __syncthreads();

  // ---- softmax per row: wave wv handles row ti = wv (waves 4..7 idle here) ----
  if (wv < TI) {
    const int ti = wv;
    float vals[8];
    float m = -3.4e38f;
    #pragma unroll
    for (int k = 0; k < 8; ++k) { vals[k] = e_l[ti][ln + 64 * k]; m = fmaxf(m, vals[k]); }
    #pragma unroll
    for (int off = 32; off > 0; off >>= 1) m = fmaxf(m, __shfl_xor(m, off, 64));
    float zs = 0.f;
    #pragma unroll
    for (int k = 0; k < 8; ++k) { vals[k] = __expf(vals[k] - m); zs += vals[k]; }
    #pragma unroll
    for (int off = 32; off > 0; off >>= 1) zs += __shfl_xor(zs, off, 64);
    float inv = 1.f / zs;
    #pragma unroll
    for (int k = 0; k < 8; ++k) e_l[ti][ln + 64 * k] = vals[k] * inv;
  }
  __syncthreads();

  // attention[0,0,:] extra output (block 0 holds b=0, i=0 in row ti=0)
  if (blk == 0 && t < NN) out[BB * NN * FF + t] = e_l[0][t];

  // ---- next_h: wave (ti = wv&3, j-half = wv>>2), lane ln owns f = 2*ln, 2*ln+1 ----
  {
    const int ti = wv & 3, jh = wv >> 2;
    const float* xb = x + b * NN * FF;
    float acc0 = 0.f, acc1 = 0.f;
    const int jend = jh * 256 + 256;
    for (int j = jh * 256; j < jend; ++j) {
      float a = e_l[ti][j];              // wave-uniform broadcast
      if (a != 0.f) {                    // masked j give exactly 0 -> uniform skip
        float2 xv = *(const float2*)(xb + j * FF + 2 * ln);
        acc0 = fmaf(a, xv.x, acc0);
        acc1 = fmaf(a, xv.y, acc1);
      }
    }
    part_l[jh][ti][2 * ln]     = acc0;
    part_l[jh][ti][2 * ln + 1] = acc1;
  }
  __syncthreads();
  if (wv < TI) {
    const int ti = wv;
    float2 r;
    r.x = part_l[0][ti][2 * ln]     + part_l[1][ti][2 * ln];
    r.y = part_l[0][ti][2 * ln + 1] + part_l[1][ti][2 * ln + 1];
    *(float2*)(out + (b * NN + i0 + ti) * FF + 2 * ln) = r;
  }
}

extern "C" void kernel_launch(void* const* d_in, const int* in_sizes, int n_in,
                              void* d_out, int out_size, void* d_ws, size_t ws_size,
                              hipStream_t stream) {
  const float* x   = (const float*)d_in[0];
  const float* w1  = (const float*)d_in[1];
  const float* b1  = (const float*)d_in[2];
  const float* w2  = (const float*)d_in[3];
  const float* b2  = (const float*)d_in[4];
  const int*   adj = (const int*)  d_in[5];
  float* out = (float*)d_out;

  float* s = (float*)d_ws;              // BB*NN*HH fp32 = 1 MB
  float* q = s + BB * NN * HH;          // BB*NN*HH fp32 = 1 MB

  k1_pq  <<<BB * NN / TN, 256, 0, stream>>>(x, w1, b1, s, q);
  k2_attn<<<BB * NN / TI, 512, 0, stream>>>(s, q, x, w2, b2, adj, out);
}

// Round 4
// 105.823 us; speedup vs baseline: 1.3907x; 1.3907x over previous
//
#include <hip/hip_runtime.h>

#define BB 2
#define NN 512
#define FF 128
#define HH 256
#define TI 4     // i-rows per K2 block

// ---------------- K1: outT = w1 . x^T ----------------
// h' in [0,512): h'<256 -> s[bn][h'] = dot(x[bn], w1[h'][0:128]) + b1[h']  (row-major)
//               h'>=256 -> qT[h'-256][bn] = dot(x[bn], w1[h'-256][128:256]) (transposed)
// lane = bn (coalesced), h-tile of 8 per block, w1/b1 via wave-uniform (scalar) loads.
#define K1_BN 256
#define K1_HT 8
#define K1_FC 32

__global__ __launch_bounds__(256) void k1_pq(const float* __restrict__ x,
    const float* __restrict__ w1, const float* __restrict__ b1,
    float* __restrict__ s_out, float* __restrict__ qT) {
  __shared__ float x_l[K1_BN][K1_FC + 1];   // 33.8 KB, padded: conflict-free per-lane reads
  const int t   = threadIdx.x;
  const int bn0 = blockIdx.x * K1_BN;
  const int h0  = blockIdx.y * K1_HT;       // h' tile base, uniform
  const bool qhalf = (h0 >= HH);
  const int wbase  = qhalf ? ((h0 - HH) * (2 * FF) + FF) : (h0 * (2 * FF));  // uniform

  float acc[K1_HT];
  #pragma unroll
  for (int k = 0; k < K1_HT; ++k) acc[k] = 0.f;

  for (int fc = 0; fc < FF; fc += K1_FC) {
    __syncthreads();
    { // stage x[bn0..+255][fc..fc+31], coalesced: 8 lanes cover 32 consecutive f
      const int r0 = t >> 3, fq = (t & 7) * 4;
      #pragma unroll
      for (int rr = 0; rr < K1_BN; rr += 32) {
        float4 v = *(const float4*)(x + (bn0 + r0 + rr) * FF + fc + fq);
        x_l[r0 + rr][fq]     = v.x;
        x_l[r0 + rr][fq + 1] = v.y;
        x_l[r0 + rr][fq + 2] = v.z;
        x_l[r0 + rr][fq + 3] = v.w;
      }
    }
    __syncthreads();
    #pragma unroll 4
    for (int f = 0; f < K1_FC; ++f) {
      float xv = x_l[t][f];                          // per-lane, conflict-free
      #pragma unroll
      for (int k = 0; k < K1_HT; ++k) {
        float wv = w1[wbase + k * (2 * FF) + fc + f]; // uniform -> s_load
        acc[k] = fmaf(xv, wv, acc[k]);
      }
    }
  }

  const int bn = bn0 + t;
  if (!qhalf) {
    #pragma unroll
    for (int k = 0; k < K1_HT; ++k) acc[k] += b1[h0 + k];  // uniform -> s_load
    float4 o0 = make_float4(acc[0], acc[1], acc[2], acc[3]);
    float4 o1 = make_float4(acc[4], acc[5], acc[6], acc[7]);
    *(float4*)(s_out + bn * HH + h0)     = o0;
    *(float4*)(s_out + bn * HH + h0 + 4) = o1;
  } else {
    #pragma unroll
    for (int k = 0; k < K1_HT; ++k)
      qT[(h0 - HH + k) * (BB * NN) + bn] = acc[k];         // coalesced
  }
}

// ---------------- K2: e -> leaky -> mask -> softmax -> next_h ----------------
// block = (b, 4 i-rows), 512 threads = 8 waves. Wave wv owns j-slice [wv*64, wv*64+64).
__global__ __launch_bounds__(512) void k2_attn(const float* __restrict__ s,
    const float* __restrict__ qT, const float* __restrict__ x,
    const float* __restrict__ w2, const float* __restrict__ b2,
    const int* __restrict__ adj, float* __restrict__ out) {
  __shared__ __align__(16) float e_l[TI][NN];          // 8 KB (e -> attention in place)
  __shared__ __align__(16) float part_l[8][TI][FF];    // 16 KB
  __shared__ float red_m[TI][2];
  __shared__ float red_s[TI][2];

  const int blk = blockIdx.x;
  const int b   = blk >> 7;                 // / 128
  const int i0  = (blk & 127) * TI;
  const int t   = threadIdx.x;              // 0..511
  const int wv  = t >> 6, ln = t & 63;
  const int j   = wv * 64 + ln;

  // ---- e-phase: acc[ti] over h; q coalesced, s/w2 wave-uniform (scalar) ----
  {
    const float* s0   = s + (b * NN + i0) * HH;        // 4 consecutive 1KB rows
    const float* qcol = qT + b * NN + j;
    float a0 = 0.f, a1 = 0.f, a2 = 0.f, a3 = 0.f;
    #pragma unroll 4
    for (int h = 0; h < HH; ++h) {
      float qv = qcol[h * (BB * NN)];                  // coalesced 4B/lane
      float wh = w2[h];                                // uniform -> s_load
      a0 = fmaf(fmaxf(s0[h]          + qv, 0.f), wh, a0);
      a1 = fmaf(fmaxf(s0[HH + h]     + qv, 0.f), wh, a1);
      a2 = fmaf(fmaxf(s0[2 * HH + h] + qv, 0.f), wh, a2);
      a3 = fmaf(fmaxf(s0[3 * HH + h] + qv, 0.f), wh, a3);
    }
    const float b2v = b2[0];
    const int* arow = adj + (b * NN + i0) * NN + j;
    float e;
    e = a0 + b2v; e = e > 0.f ? e : 0.04f * e; e_l[0][j] = (arow[0]      > 0) ? e : -9.0e15f;
    e = a1 + b2v; e = e > 0.f ? e : 0.04f * e; e_l[1][j] = (arow[NN]     > 0) ? e : -9.0e15f;
    e = a2 + b2v; e = e > 0.f ? e : 0.04f * e; e_l[2][j] = (arow[2 * NN] > 0) ? e : -9.0e15f;
    e = a3 + b2v; e = e > 0.f ? e : 0.04f * e; e_l[3][j] = (arow[3 * NN] > 0) ? e : -9.0e15f;
  }
  __syncthreads();

  // ---- softmax: wave = (ti = wv&3, half = wv>>2), 4 values per lane ----
  {
    const int ti = wv & 3, hf = wv >> 2;
    float4 v = *(float4*)&e_l[ti][hf * 256 + 4 * ln];
    float m = fmaxf(fmaxf(v.x, v.y), fmaxf(v.z, v.w));
    #pragma unroll
    for (int off = 32; off > 0; off >>= 1) m = fmaxf(m, __shfl_xor(m, off, 64));
    if (ln == 0) red_m[ti][hf] = m;
    __syncthreads();
    m = fmaxf(red_m[ti][0], red_m[ti][1]);
    v.x = __expf(v.x - m); v.y = __expf(v.y - m);
    v.z = __expf(v.z - m); v.w = __expf(v.w - m);
    float zs = (v.x + v.y) + (v.z + v.w);
    #pragma unroll
    for (int off = 32; off > 0; off >>= 1) zs += __shfl_xor(zs, off, 64);
    if (ln == 0) red_s[ti][hf] = zs;
    __syncthreads();
    float inv = 1.f / (red_s[ti][0] + red_s[ti][1]);
    v.x *= inv; v.y *= inv; v.z *= inv; v.w *= inv;
    *(float4*)&e_l[ti][hf * 256 + 4 * ln] = v;
  }
  __syncthreads();

  // attention[0,0,:] extra output
  if (blk == 0) out[BB * NN * FF + t] = e_l[0][t];

  // ---- next_h: wave wv's 64-j slice; lane = (j-half, f-quad); 4ti x 4f regs ----
  {
    const int hf = ln >> 5;               // which 32-j half of the slice
    const int fq = (ln & 31) * 4;
    const int jb = wv * 64 + hf * 32;
    float4 acc[TI];
    #pragma unroll
    for (int ti = 0; ti < TI; ++ti) acc[ti] = make_float4(0.f, 0.f, 0.f, 0.f);

    for (int s8 = 0; s8 < 8; ++s8) {
      const int j0 = jb + s8 * 4;
      float4 aa[TI];
      #pragma unroll
      for (int ti = 0; ti < TI; ++ti) aa[ti] = *(float4*)&e_l[ti][j0];  // 2-addr broadcast
      #pragma unroll
      for (int jj = 0; jj < 4; ++jj) {
        float4 xv = *(const float4*)(x + (b * NN + j0 + jj) * FF + fq); // 2x512B coalesced
        #pragma unroll
        for (int ti = 0; ti < TI; ++ti) {
          float w = (jj == 0) ? aa[ti].x : (jj == 1) ? aa[ti].y : (jj == 2) ? aa[ti].z : aa[ti].w;
          acc[ti].x = fmaf(w, xv.x, acc[ti].x);
          acc[ti].y = fmaf(w, xv.y, acc[ti].y);
          acc[ti].z = fmaf(w, xv.z, acc[ti].z);
          acc[ti].w = fmaf(w, xv.w, acc[ti].w);
        }
      }
    }
    // combine the two 32-j halves, then deposit per-wave partials
    #pragma unroll
    for (int ti = 0; ti < TI; ++ti) {
      acc[ti].x += __shfl_xor(acc[ti].x, 32, 64);
      acc[ti].y += __shfl_xor(acc[ti].y, 32, 64);
      acc[ti].z += __shfl_xor(acc[ti].z, 32, 64);
      acc[ti].w += __shfl_xor(acc[ti].w, 32, 64);
    }
    if (ln < 32) {
      #pragma unroll
      for (int ti = 0; ti < TI; ++ti)
        *(float4*)&part_l[wv][ti][fq] = acc[ti];
    }
  }
  __syncthreads();
  { // final cross-wave reduction + store
    const int ti = t >> 7, f = t & 127;
    float r = 0.f;
    #pragma unroll
    for (int w = 0; w < 8; ++w) r += part_l[w][ti][f];
    out[(b * NN + i0 + ti) * FF + f] = r;
  }
}

extern "C" void kernel_launch(void* const* d_in, const int* in_sizes, int n_in,
                              void* d_out, int out_size, void* d_ws, size_t ws_size,
                              hipStream_t stream) {
  const float* x   = (const float*)d_in[0];
  const float* w1  = (const float*)d_in[1];
  const float* b1  = (const float*)d_in[2];
  const float* w2  = (const float*)d_in[3];
  const float* b2  = (const float*)d_in[4];
  const int*   adj = (const int*)  d_in[5];
  float* out = (float*)d_out;

  float* s  = (float*)d_ws;                 // [1024][256] fp32 = 1 MB, row-major
  float* qT = s + BB * NN * HH;             // [256][1024] fp32 = 1 MB, transposed

  dim3 g1(BB * NN / K1_BN, (2 * HH) / K1_HT);   // (4, 64)
  k1_pq  <<<g1, K1_BN, 0, stream>>>(x, w1, b1, s, qT);
  k2_attn<<<BB * NN / TI, 512, 0, stream>>>(s, qT, x, w2, b2, adj, out);
}

// Round 5
// 93.318 us; speedup vs baseline: 1.5771x; 1.1340x over previous
//
#include <hip/hip_runtime.h>

#define BB 2
#define NN 512
#define FF 128
#define HH 256
#define TI 4     // i-rows per K2 block

// ---------------- K1: s / qT = x . w1 halves ----------------
// Block: 16 bn x 64 h'. Grid (64, 8). h' = by*64 + lane.
// w1 tile in LDS, column-rotated by 4*row -> conflict-free ds_read_b128.
// x rows are wave-uniform -> forced scalar loads.
__global__ __launch_bounds__(256) void k1_pq(const float* __restrict__ x,
    const float* __restrict__ w1, const float* __restrict__ b1,
    float* __restrict__ s_out, float* __restrict__ qT) {
  __shared__ __align__(16) float w1_l[64][FF];   // 32 KB, rotated
  __shared__ float qtmp[64][17];                 // 4.25 KB (q-half transpose)
  const int t   = threadIdx.x;
  const int bn0 = blockIdx.x * 16;
  const int h0  = blockIdx.y * 64;               // h' base
  const bool qh = (h0 >= HH);
  const int rowbase = qh ? (h0 - HH) : h0;
  const int colbase = qh ? FF : 0;

  // stage w1 tile: element (r, f) stored at column (f + 4r) & 127
  #pragma unroll
  for (int k = 0; k < 8; ++k) {
    int idx = t + 256 * k;
    int r = idx >> 5, c4 = (idx & 31) * 4;
    float4 v = *(const float4*)(w1 + (rowbase + r) * (2 * FF) + colbase + c4);
    *(float4*)&w1_l[r][(c4 + 4 * r) & 127] = v;
  }
  __syncthreads();

  const int l  = t & 63;
  const int sb = __builtin_amdgcn_readfirstlane(t >> 6);   // wave-uniform bn group
  const float* xr = x + (bn0 + sb * 4) * FF;
  float acc0 = 0.f, acc1 = 0.f, acc2 = 0.f, acc3 = 0.f;

  #pragma unroll 4
  for (int f4 = 0; f4 < FF; f4 += 4) {
    float4 wv = *(float4*)&w1_l[l][(f4 + 4 * l) & 127];
    float4 x0 = *(const float4*)(xr + f4);            // uniform -> s_load
    float4 x1 = *(const float4*)(xr + FF + f4);
    float4 x2 = *(const float4*)(xr + 2 * FF + f4);
    float4 x3 = *(const float4*)(xr + 3 * FF + f4);
    acc0 = fmaf(x0.x, wv.x, acc0); acc0 = fmaf(x0.y, wv.y, acc0);
    acc0 = fmaf(x0.z, wv.z, acc0); acc0 = fmaf(x0.w, wv.w, acc0);
    acc1 = fmaf(x1.x, wv.x, acc1); acc1 = fmaf(x1.y, wv.y, acc1);
    acc1 = fmaf(x1.z, wv.z, acc1); acc1 = fmaf(x1.w, wv.w, acc1);
    acc2 = fmaf(x2.x, wv.x, acc2); acc2 = fmaf(x2.y, wv.y, acc2);
    acc2 = fmaf(x2.z, wv.z, acc2); acc2 = fmaf(x2.w, wv.w, acc2);
    acc3 = fmaf(x3.x, wv.x, acc3); acc3 = fmaf(x3.y, wv.y, acc3);
    acc3 = fmaf(x3.z, wv.z, acc3); acc3 = fmaf(x3.w, wv.w, acc3);
  }

  const int bn = bn0 + sb * 4;
  if (!qh) {
    float bv = b1[h0 + l];                             // coalesced 256B
    s_out[(bn    ) * HH + h0 + l] = acc0 + bv;
    s_out[(bn + 1) * HH + h0 + l] = acc1 + bv;
    s_out[(bn + 2) * HH + h0 + l] = acc2 + bv;
    s_out[(bn + 3) * HH + h0 + l] = acc3 + bv;
  } else {
    qtmp[l][sb * 4]     = acc0;
    qtmp[l][sb * 4 + 1] = acc1;
    qtmp[l][sb * 4 + 2] = acc2;
    qtmp[l][sb * 4 + 3] = acc3;
    __syncthreads();
    #pragma unroll
    for (int k = 0; k < 4; ++k) {     // 64 h' x 16 bn, coalesced-ish stores
      int idx = t + 256 * k;
      int r = idx >> 4, c = idx & 15;
      qT[(h0 - HH + r) * (BB * NN) + bn0 + c] = qtmp[r][c];
    }
  }
}

// ---------------- K2: e -> leaky -> mask -> softmax -> next_h ----------------
// Block = (b, 4 i-rows), 1024 threads = 16 waves (4/SIMD).
__global__ __launch_bounds__(1024) void k2_attn(const float* __restrict__ s,
    const float* __restrict__ qT, const float* __restrict__ x,
    const float* __restrict__ w2, const float* __restrict__ b2,
    const int* __restrict__ adj, float* __restrict__ out) {
  __shared__ __align__(16) float e_l[TI][NN];          // 8 KB
  __shared__ __align__(16) float pe[2][TI][NN];        // 16 KB (h-half partials)
  __shared__ __align__(16) float part_l[4][TI][FF];    // 8 KB
  __shared__ float red_m[TI][4];
  __shared__ float red_s[TI][4];

  const int blk = blockIdx.x;
  const int b   = blk >> 7;                 // / 128
  const int i0  = (blk & 127) * TI;
  const int t   = threadIdx.x;              // 0..1023
  const int wv  = __builtin_amdgcn_readfirstlane(t >> 6);
  const int ln  = t & 63;

  // ---- e-phase: wave = (h-half hg, 64-j slice); q coalesced, s/w2 scalar ----
  {
    const int hg = wv >> 3;                 // 0/1 -> h in [hg*128, +128)
    const int j  = (wv & 7) * 64 + ln;
    const float* qcol = qT + hg * 128 * (BB * NN) + b * NN + j;
    const float* s0   = s + (b * NN + i0) * HH + hg * 128;
    const float* w2p  = w2 + hg * 128;
    float a0 = 0.f, a1 = 0.f, a2 = 0.f, a3 = 0.f;
    #pragma unroll 8
    for (int h = 0; h < 128; ++h) {
      float qv = qcol[h * (BB * NN)];       // coalesced 256B
      float wh = w2p[h];                    // scalar
      a0 = fmaf(fmaxf(s0[h]          + qv, 0.f), wh, a0);
      a1 = fmaf(fmaxf(s0[HH + h]     + qv, 0.f), wh, a1);
      a2 = fmaf(fmaxf(s0[2 * HH + h] + qv, 0.f), wh, a2);
      a3 = fmaf(fmaxf(s0[3 * HH + h] + qv, 0.f), wh, a3);
    }
    pe[hg][0][j] = a0; pe[hg][1][j] = a1;
    pe[hg][2][j] = a2; pe[hg][3][j] = a3;
  }
  __syncthreads();

  // ---- combine h-halves + bias + leaky + mask ----
  {
    const float b2v = b2[0];
    #pragma unroll
    for (int r = 0; r < 2; ++r) {
      int idx = t + 1024 * r;               // 2048 cells of [ti][j]
      int ti = idx >> 9, j2 = idx & 511;
      float e = pe[0][ti][j2] + pe[1][ti][j2] + b2v;
      e = e > 0.f ? e : 0.04f * e;
      int av = adj[(b * NN + i0 + ti) * NN + j2];
      e_l[ti][j2] = (av > 0) ? e : -9.0e15f;
    }
  }
  __syncthreads();

  // ---- softmax: wave = (ti = wv>>2, j-quarter = wv&3), 2 vals/lane ----
  {
    const int ti = wv >> 2, qtr = wv & 3;
    float2 v = *(float2*)&e_l[ti][qtr * 128 + 2 * ln];
    float m = fmaxf(v.x, v.y);
    #pragma unroll
    for (int off = 32; off > 0; off >>= 1) m = fmaxf(m, __shfl_xor(m, off, 64));
    if (ln == 0) red_m[ti][qtr] = m;
    __syncthreads();
    m = fmaxf(fmaxf(red_m[ti][0], red_m[ti][1]), fmaxf(red_m[ti][2], red_m[ti][3]));
    v.x = __expf(v.x - m); v.y = __expf(v.y - m);
    float zs = v.x + v.y;
    #pragma unroll
    for (int off = 32; off > 0; off >>= 1) zs += __shfl_xor(zs, off, 64);
    if (ln == 0) red_s[ti][qtr] = zs;
    __syncthreads();
    float inv = 1.f / ((red_s[ti][0] + red_s[ti][1]) + (red_s[ti][2] + red_s[ti][3]));
    v.x *= inv; v.y *= inv;
    *(float2*)&e_l[ti][qtr * 128 + 2 * ln] = v;
  }
  __syncthreads();

  // attention[0,0,:] extra output
  if (blk == 0 && t < NN) out[BB * NN * FF + t] = e_l[0][t];

  // ---- next_h: wave = (ti = wv&3, j-quarter = wv>>2); lane = (j-half, f-quad) ----
  {
    const int ti = wv & 3, qtr = wv >> 2;
    const int jh = ln >> 5, fq = (ln & 31) * 4;
    const int jb = qtr * 128 + jh * 64;
    float4 acc = make_float4(0.f, 0.f, 0.f, 0.f);
    for (int s4 = 0; s4 < 16; ++s4) {
      const int j0 = jb + s4 * 4;
      float4 aa = *(float4*)&e_l[ti][j0];                 // 2-addr broadcast
      #pragma unroll
      for (int jj = 0; jj < 4; ++jj) {
        float4 xv = *(const float4*)(x + (b * NN + j0 + jj) * FF + fq);
        float w = (jj == 0) ? aa.x : (jj == 1) ? aa.y : (jj == 2) ? aa.z : aa.w;
        acc.x = fmaf(w, xv.x, acc.x);
        acc.y = fmaf(w, xv.y, acc.y);
        acc.z = fmaf(w, xv.z, acc.z);
        acc.w = fmaf(w, xv.w, acc.w);
      }
    }
    acc.x += __shfl_xor(acc.x, 32, 64);
    acc.y += __shfl_xor(acc.y, 32, 64);
    acc.z += __shfl_xor(acc.z, 32, 64);
    acc.w += __shfl_xor(acc.w, 32, 64);
    if (ln < 32) *(float4*)&part_l[qtr][ti][fq] = acc;
  }
  __syncthreads();
  if (t < TI * FF) {                         // 512 cells
    const int ti = t >> 7, f = t & 127;
    float r = (part_l[0][ti][f] + part_l[1][ti][f])
            + (part_l[2][ti][f] + part_l[3][ti][f]);
    out[(b * NN + i0 + ti) * FF + f] = r;
  }
}

extern "C" void kernel_launch(void* const* d_in, const int* in_sizes, int n_in,
                              void* d_out, int out_size, void* d_ws, size_t ws_size,
                              hipStream_t stream) {
  const float* x   = (const float*)d_in[0];
  const float* w1  = (const float*)d_in[1];
  const float* b1  = (const float*)d_in[2];
  const float* w2  = (const float*)d_in[3];
  const float* b2  = (const float*)d_in[4];
  const int*   adj = (const int*)  d_in[5];
  float* out = (float*)d_out;

  float* s  = (float*)d_ws;                 // [1024][256] fp32 = 1 MB, row-major
  float* qT = s + BB * NN * HH;             // [256][1024] fp32 = 1 MB, transposed

  dim3 g1(BB * NN / 16, (2 * HH) / 64);     // (64, 8) = 512 blocks
  k1_pq  <<<g1, 256, 0, stream>>>(x, w1, b1, s, qT);
  k2_attn<<<BB * NN / TI, 1024, 0, stream>>>(s, qT, x, w2, b2, adj, out);
}

// Round 6
// 89.776 us; speedup vs baseline: 1.6393x; 1.0395x over previous
//
#include <hip/hip_runtime.h>

#define BB 2
#define NN 512
#define FF 128
#define HH 256
#define TI 4     // i-rows per K2 block

typedef float v2f __attribute__((ext_vector_type(2)));
__device__ __forceinline__ v2f splat2(float s) { return (v2f){s, s}; }

// ---------------- K1: s / qT = x . w1 halves ---------------- (unchanged, proven)
__global__ __launch_bounds__(256) void k1_pq(const float* __restrict__ x,
    const float* __restrict__ w1, const float* __restrict__ b1,
    float* __restrict__ s_out, float* __restrict__ qT) {
  __shared__ __align__(16) float w1_l[64][FF];   // 32 KB, rotated
  __shared__ float qtmp[64][17];                 // 4.25 KB (q-half transpose)
  const int t   = threadIdx.x;
  const int bn0 = blockIdx.x * 16;
  const int h0  = blockIdx.y * 64;               // h' base
  const bool qh = (h0 >= HH);
  const int rowbase = qh ? (h0 - HH) : h0;
  const int colbase = qh ? FF : 0;

  #pragma unroll
  for (int k = 0; k < 8; ++k) {
    int idx = t + 256 * k;
    int r = idx >> 5, c4 = (idx & 31) * 4;
    float4 v = *(const float4*)(w1 + (rowbase + r) * (2 * FF) + colbase + c4);
    *(float4*)&w1_l[r][(c4 + 4 * r) & 127] = v;
  }
  __syncthreads();

  const int l  = t & 63;
  const int sb = __builtin_amdgcn_readfirstlane(t >> 6);
  const float* xr = x + (bn0 + sb * 4) * FF;
  float acc0 = 0.f, acc1 = 0.f, acc2 = 0.f, acc3 = 0.f;

  #pragma unroll 4
  for (int f4 = 0; f4 < FF; f4 += 4) {
    float4 wv = *(float4*)&w1_l[l][(f4 + 4 * l) & 127];
    float4 x0 = *(const float4*)(xr + f4);
    float4 x1 = *(const float4*)(xr + FF + f4);
    float4 x2 = *(const float4*)(xr + 2 * FF + f4);
    float4 x3 = *(const float4*)(xr + 3 * FF + f4);
    acc0 = fmaf(x0.x, wv.x, acc0); acc0 = fmaf(x0.y, wv.y, acc0);
    acc0 = fmaf(x0.z, wv.z, acc0); acc0 = fmaf(x0.w, wv.w, acc0);
    acc1 = fmaf(x1.x, wv.x, acc1); acc1 = fmaf(x1.y, wv.y, acc1);
    acc1 = fmaf(x1.z, wv.z, acc1); acc1 = fmaf(x1.w, wv.w, acc1);
    acc2 = fmaf(x2.x, wv.x, acc2); acc2 = fmaf(x2.y, wv.y, acc2);
    acc2 = fmaf(x2.z, wv.z, acc2); acc2 = fmaf(x2.w, wv.w, acc2);
    acc3 = fmaf(x3.x, wv.x, acc3); acc3 = fmaf(x3.y, wv.y, acc3);
    acc3 = fmaf(x3.z, wv.z, acc3); acc3 = fmaf(x3.w, wv.w, acc3);
  }

  const int bn = bn0 + sb * 4;
  if (!qh) {
    float bv = b1[h0 + l];
    s_out[(bn    ) * HH + h0 + l] = acc0 + bv;
    s_out[(bn + 1) * HH + h0 + l] = acc1 + bv;
    s_out[(bn + 2) * HH + h0 + l] = acc2 + bv;
    s_out[(bn + 3) * HH + h0 + l] = acc3 + bv;
  } else {
    qtmp[l][sb * 4]     = acc0;
    qtmp[l][sb * 4 + 1] = acc1;
    qtmp[l][sb * 4 + 2] = acc2;
    qtmp[l][sb * 4 + 3] = acc3;
    __syncthreads();
    #pragma unroll
    for (int k = 0; k < 4; ++k) {
      int idx = t + 256 * k;
      int r = idx >> 4, c = idx & 15;
      qT[(h0 - HH + r) * (BB * NN) + bn0 + c] = qtmp[r][c];
    }
  }
}

// ---------------- K2: e -> leaky -> mask -> softmax -> next_h ----------------
// Block = (b, 4 i-rows), 1024 threads = 16 waves. Packed fp32 (v_pk_fma_f32).
__global__ __launch_bounds__(1024) void k2_attn(const float* __restrict__ s,
    const float* __restrict__ qT, const float* __restrict__ x,
    const float* __restrict__ w2, const float* __restrict__ b2,
    const int* __restrict__ adj, float* __restrict__ out) {
  __shared__ __align__(16) float pe[4][TI][NN];        // 32 KB (h-quarter partials)
  __shared__ __align__(16) float e_l[TI][NN];          // 8 KB
  __shared__ __align__(16) float part_l[16][TI][FF];   // 32 KB
  __shared__ float red_m[TI][4];
  __shared__ float red_s[TI][4];

  const int blk = blockIdx.x;
  const int b   = blk >> 7;                 // / 128
  const int i0  = (blk & 127) * TI;
  const int t   = threadIdx.x;              // 0..1023
  const int wv  = __builtin_amdgcn_readfirstlane(t >> 6);
  const int ln  = t & 63;

  // ---- e-phase: wave = (h-quarter hq, 128-j slice sl); 2 j packed per lane ----
  {
    const int hq = wv >> 2;                 // h in [hq*64, +64)
    const int sl = wv & 3;                  // j in [sl*128, +128), lane pair j0=sl*128+2ln
    const int j0 = sl * 128 + 2 * ln;
    const float* qp  = qT + hq * 64 * (BB * NN) + b * NN + j0;
    const float* s0  = s + (b * NN + i0) * HH + hq * 64;   // uniform -> s_load
    const float* w2p = w2 + hq * 64;                       // uniform -> s_load
    v2f a0 = {0.f, 0.f}, a1 = {0.f, 0.f}, a2 = {0.f, 0.f}, a3 = {0.f, 0.f};
    #pragma unroll 8
    for (int h = 0; h < 64; ++h) {
      v2f q2 = *(const v2f*)(qp + h * (BB * NN));          // coalesced 8B/lane
      v2f w2v = splat2(w2p[h]);
      v2f z = {0.f, 0.f};
      v2f t0 = __builtin_elementwise_max(splat2(s0[h])           + q2, z);
      v2f t1 = __builtin_elementwise_max(splat2(s0[HH + h])      + q2, z);
      v2f t2 = __builtin_elementwise_max(splat2(s0[2 * HH + h])  + q2, z);
      v2f t3 = __builtin_elementwise_max(splat2(s0[3 * HH + h])  + q2, z);
      a0 = __builtin_elementwise_fma(t0, w2v, a0);
      a1 = __builtin_elementwise_fma(t1, w2v, a1);
      a2 = __builtin_elementwise_fma(t2, w2v, a2);
      a3 = __builtin_elementwise_fma(t3, w2v, a3);
    }
    *(v2f*)&pe[hq][0][j0] = a0;
    *(v2f*)&pe[hq][1][j0] = a1;
    *(v2f*)&pe[hq][2][j0] = a2;
    *(v2f*)&pe[hq][3][j0] = a3;
  }
  __syncthreads();

  // ---- combine h-quarters + bias + leaky + mask ----
  {
    const float b2v = b2[0];
    #pragma unroll
    for (int r = 0; r < 2; ++r) {
      int idx = t + 1024 * r;               // 2048 cells of [ti][j]
      int ti = idx >> 9, j2 = idx & 511;
      float e = (pe[0][ti][j2] + pe[1][ti][j2]) + (pe[2][ti][j2] + pe[3][ti][j2]) + b2v;
      e = e > 0.f ? e : 0.04f * e;
      int av = adj[(b * NN + i0 + ti) * NN + j2];
      e_l[ti][j2] = (av > 0) ? e : -9.0e15f;
    }
  }
  __syncthreads();

  // ---- softmax: wave = (ti = wv>>2, j-quarter = wv&3), 2 vals/lane ----
  {
    const int ti = wv >> 2, qtr = wv & 3;
    float2 v = *(float2*)&e_l[ti][qtr * 128 + 2 * ln];
    float m = fmaxf(v.x, v.y);
    #pragma unroll
    for (int off = 32; off > 0; off >>= 1) m = fmaxf(m, __shfl_xor(m, off, 64));
    if (ln == 0) red_m[ti][qtr] = m;
    __syncthreads();
    m = fmaxf(fmaxf(red_m[ti][0], red_m[ti][1]), fmaxf(red_m[ti][2], red_m[ti][3]));
    v.x = __expf(v.x - m); v.y = __expf(v.y - m);
    float zs = v.x + v.y;
    #pragma unroll
    for (int off = 32; off > 0; off >>= 1) zs += __shfl_xor(zs, off, 64);
    if (ln == 0) red_s[ti][qtr] = zs;
    __syncthreads();
    float inv = 1.f / ((red_s[ti][0] + red_s[ti][1]) + (red_s[ti][2] + red_s[ti][3]));
    v.x *= inv; v.y *= inv;
    *(float2*)&e_l[ti][qtr * 128 + 2 * ln] = v;
  }
  __syncthreads();

  // attention[0,0,:] extra output
  if (blk == 0 && t < NN) out[BB * NN * FF + t] = e_l[0][t];

  // ---- next_h: wave wv owns 32 j-rows (read x once per block); lane = f-pair ----
  {
    const int jb = wv * 32;
    const int f2 = 2 * ln;
    v2f acc[TI];
    #pragma unroll
    for (int ti = 0; ti < TI; ++ti) acc[ti] = (v2f){0.f, 0.f};

    #pragma unroll 2
    for (int g = 0; g < 8; ++g) {
      const int j0 = jb + g * 4;
      float4 aa[TI];
      #pragma unroll
      for (int ti = 0; ti < TI; ++ti) aa[ti] = *(float4*)&e_l[ti][j0];  // broadcast b128
      #pragma unroll
      for (int k = 0; k < 4; ++k) {
        v2f x2 = *(const v2f*)(x + (b * NN + j0 + k) * FF + f2);        // coalesced 512B
        #pragma unroll
        for (int ti = 0; ti < TI; ++ti) {
          float w = (k == 0) ? aa[ti].x : (k == 1) ? aa[ti].y : (k == 2) ? aa[ti].z : aa[ti].w;
          acc[ti] = __builtin_elementwise_fma(splat2(w), x2, acc[ti]);
        }
      }
    }
    #pragma unroll
    for (int ti = 0; ti < TI; ++ti) *(v2f*)&part_l[wv][ti][f2] = acc[ti];
  }
  __syncthreads();
  if (t < TI * FF) {                         // 512 cells
    const int ti = t >> 7, f = t & 127;
    float r = 0.f;
    #pragma unroll
    for (int w = 0; w < 16; ++w) r += part_l[w][ti][f];
    out[(b * NN + i0 + ti) * FF + f] = r;
  }
}

extern "C" void kernel_launch(void* const* d_in, const int* in_sizes, int n_in,
                              void* d_out, int out_size, void* d_ws, size_t ws_size,
                              hipStream_t stream) {
  const float* x   = (const float*)d_in[0];
  const float* w1  = (const float*)d_in[1];
  const float* b1  = (const float*)d_in[2];
  const float* w2  = (const float*)d_in[3];
  const float* b2  = (const float*)d_in[4];
  const int*   adj = (const int*)  d_in[5];
  float* out = (float*)d_out;

  float* s  = (float*)d_ws;                 // [1024][256] fp32 = 1 MB, row-major
  float* qT = s + BB * NN * HH;             // [256][1024] fp32 = 1 MB, transposed

  dim3 g1(BB * NN / 16, (2 * HH) / 64);     // (64, 8) = 512 blocks
  k1_pq  <<<g1, 256, 0, stream>>>(x, w1, b1, s, qT);
  k2_attn<<<BB * NN / TI, 1024, 0, stream>>>(s, qT, x, w2, b2, adj, out);
}

// Round 7
// 85.796 us; speedup vs baseline: 1.7154x; 1.0464x over previous
//
#include <hip/hip_runtime.h>

#define BB 2
#define NN 512
#define FF 128
#define HH 256
#define TI 4     // i-rows per K2 block

typedef float v2f __attribute__((ext_vector_type(2)));
typedef _Float16 v2h __attribute__((ext_vector_type(2)));
typedef unsigned int u32;
__device__ __forceinline__ v2f splat2(float s) { return (v2f){s, s}; }

#if defined(__has_builtin)
#if __has_builtin(__builtin_amdgcn_fdot2)
#define HAVE_DOT2 1
#endif
#endif

__device__ __forceinline__ u32 pack16(float a, float b) {
  v2h p; p.x = (_Float16)a; p.y = (_Float16)b;
  return __builtin_bit_cast(u32, p);
}
__device__ __forceinline__ v2h as_v2h(u32 u) { return __builtin_bit_cast(v2h, u); }

// ---------------- K1: s16 / qT16 = f16-packed x . w1 halves ----------------
// Grid (64, 8). h0 = by*64. by<4 -> s-half (s16[bn][h] f16, +b1 folded);
// by>=4 -> q-half (qT16[hp][bn] u32 = packed h-pair). w216 written by one block.
__global__ __launch_bounds__(256) void k1_pq(const float* __restrict__ x,
    const float* __restrict__ w1, const float* __restrict__ b1,
    const float* __restrict__ w2,
    u32* __restrict__ s16, u32* __restrict__ q16, u32* __restrict__ w216) {
  __shared__ __align__(16) float w1_l[64][FF];   // 32 KB, rotated
  __shared__ float tmp[64][17];                  // transpose buffer (q-half)
  const int t   = threadIdx.x;
  const int bn0 = blockIdx.x * 16;
  const int h0  = blockIdx.y * 64;               // h' base
  const bool qh = (h0 >= HH);
  const int rowbase = qh ? (h0 - HH) : h0;
  const int colbase = qh ? FF : 0;

  #pragma unroll
  for (int k = 0; k < 8; ++k) {
    int idx = t + 256 * k;
    int r = idx >> 5, c4 = (idx & 31) * 4;
    float4 v = *(const float4*)(w1 + (rowbase + r) * (2 * FF) + colbase + c4);
    *(float4*)&w1_l[r][(c4 + 4 * r) & 127] = v;
  }
  __syncthreads();

  const int l  = t & 63;
  const int sb = __builtin_amdgcn_readfirstlane(t >> 6);
  const float* xr = x + (bn0 + sb * 4) * FF;
  float acc0 = 0.f, acc1 = 0.f, acc2 = 0.f, acc3 = 0.f;

  #pragma unroll 4
  for (int f4 = 0; f4 < FF; f4 += 4) {
    float4 wv = *(float4*)&w1_l[l][(f4 + 4 * l) & 127];
    float4 x0 = *(const float4*)(xr + f4);
    float4 x1 = *(const float4*)(xr + FF + f4);
    float4 x2 = *(const float4*)(xr + 2 * FF + f4);
    float4 x3 = *(const float4*)(xr + 3 * FF + f4);
    acc0 = fmaf(x0.x, wv.x, acc0); acc0 = fmaf(x0.y, wv.y, acc0);
    acc0 = fmaf(x0.z, wv.z, acc0); acc0 = fmaf(x0.w, wv.w, acc0);
    acc1 = fmaf(x1.x, wv.x, acc1); acc1 = fmaf(x1.y, wv.y, acc1);
    acc1 = fmaf(x1.z, wv.z, acc1); acc1 = fmaf(x1.w, wv.w, acc1);
    acc2 = fmaf(x2.x, wv.x, acc2); acc2 = fmaf(x2.y, wv.y, acc2);
    acc2 = fmaf(x2.z, wv.z, acc2); acc2 = fmaf(x2.w, wv.w, acc2);
    acc3 = fmaf(x3.x, wv.x, acc3); acc3 = fmaf(x3.y, wv.y, acc3);
    acc3 = fmaf(x3.z, wv.z, acc3); acc3 = fmaf(x3.w, wv.w, acc3);
  }

  const int bn = bn0 + sb * 4;
  if (!qh) {
    float bv = b1[h0 + l];
    ushort* sp = (ushort*)s16;                   // s16 as [bn][h] f16
    sp[(bn    ) * HH + h0 + l] = __builtin_bit_cast(ushort, (_Float16)(acc0 + bv));
    sp[(bn + 1) * HH + h0 + l] = __builtin_bit_cast(ushort, (_Float16)(acc1 + bv));
    sp[(bn + 2) * HH + h0 + l] = __builtin_bit_cast(ushort, (_Float16)(acc2 + bv));
    sp[(bn + 3) * HH + h0 + l] = __builtin_bit_cast(ushort, (_Float16)(acc3 + bv));
  } else {
    tmp[l][sb * 4]     = acc0;
    tmp[l][sb * 4 + 1] = acc1;
    tmp[l][sb * 4 + 2] = acc2;
    tmp[l][sb * 4 + 3] = acc3;
    __syncthreads();
    #pragma unroll
    for (int k = 0; k < 2; ++k) {                // 32 hp x 16 bn packed pairs
      int idx = t + 256 * k;
      int rp = idx >> 4, c = idx & 15;
      q16[((h0 - HH) / 2 + rp) * (BB * NN) + bn0 + c] =
          pack16(tmp[2 * rp][c], tmp[2 * rp + 1][c]);
    }
    if (blockIdx.x == 0 && h0 == HH && t < HH / 2)
      w216[t] = pack16(w2[2 * t], w2[2 * t + 1]);
  }
}

// ---------------- K2: e -> leaky -> mask -> softmax -> next_h ----------------
// Block = (b, 4 i-rows), 1024 threads = 16 waves.
// e-phase: wave = (h-half hg, 64-j slice sl); f16 dot2 (2 MAC/instr), fp32 acc.
__global__ __launch_bounds__(1024) void k2_attn(const u32* __restrict__ s16,
    const u32* __restrict__ q16, const u32* __restrict__ w216,
    const float* __restrict__ x, const float* __restrict__ b2,
    const int* __restrict__ adj, float* __restrict__ out) {
  __shared__ __align__(16) float pe[2][TI][NN];        // 16 KB (h-half partials)
  __shared__ __align__(16) float e_l[TI][NN];          // 8 KB
  __shared__ __align__(16) float part_l[16][TI][FF];   // 32 KB
  __shared__ float red_m[TI][4];
  __shared__ float red_s[TI][4];

  const int blk = blockIdx.x;
  const int b   = blk >> 7;                 // / 128
  const int i0  = (blk & 127) * TI;
  const int t   = threadIdx.x;              // 0..1023
  const int wv  = __builtin_amdgcn_readfirstlane(t >> 6);
  const int ln  = t & 63;

  // ---- e-phase ----
  {
    const int hg = wv >> 3;                 // h-pair range [hg*64, +64)
    const int sl = wv & 7;                  // j slice, lane j = sl*64+ln
    const int j  = sl * 64 + ln;
    const u32* qp = q16 + hg * 64 * (BB * NN) + b * NN + j;
    const u32* sp = s16 + (b * NN + i0) * (HH / 2) + hg * 64;  // uniform -> s_load
    const u32* wp = w216 + hg * 64;                            // uniform -> s_load
    float a0 = 0.f, a1 = 0.f, a2 = 0.f, a3 = 0.f;
#ifdef HAVE_DOT2
    const v2h z2 = {(_Float16)0.f, (_Float16)0.f};
    #pragma unroll 8
    for (int hp = 0; hp < 64; ++hp) {
      v2h q2 = as_v2h(qp[hp * (BB * NN)]);  // coalesced 4B/lane
      v2h wh = as_v2h(wp[hp]);
      v2h s0 = as_v2h(sp[hp]);
      v2h s1 = as_v2h(sp[HH / 2 + hp]);
      v2h s2 = as_v2h(sp[2 * (HH / 2) + hp]);
      v2h s3 = as_v2h(sp[3 * (HH / 2) + hp]);
      a0 = __builtin_amdgcn_fdot2(__builtin_elementwise_max(s0 + q2, z2), wh, a0, false);
      a1 = __builtin_amdgcn_fdot2(__builtin_elementwise_max(s1 + q2, z2), wh, a1, false);
      a2 = __builtin_amdgcn_fdot2(__builtin_elementwise_max(s2 + q2, z2), wh, a2, false);
      a3 = __builtin_amdgcn_fdot2(__builtin_elementwise_max(s3 + q2, z2), wh, a3, false);
    }
#else
    #pragma unroll 8
    for (int hp = 0; hp < 64; ++hp) {
      v2h q2 = as_v2h(qp[hp * (BB * NN)]);
      v2h wh = as_v2h(wp[hp]);
      v2h s0 = as_v2h(sp[hp]);
      v2h s1 = as_v2h(sp[HH / 2 + hp]);
      v2h s2 = as_v2h(sp[2 * (HH / 2) + hp]);
      v2h s3 = as_v2h(sp[3 * (HH / 2) + hp]);
      float qx = (float)q2.x, qy = (float)q2.y;
      float wx = (float)wh.x, wy = (float)wh.y;
      a0 = fmaf(fmaxf((float)s0.x + qx, 0.f), wx, a0);
      a0 = fmaf(fmaxf((float)s0.y + qy, 0.f), wy, a0);
      a1 = fmaf(fmaxf((float)s1.x + qx, 0.f), wx, a1);
      a1 = fmaf(fmaxf((float)s1.y + qy, 0.f), wy, a1);
      a2 = fmaf(fmaxf((float)s2.x + qx, 0.f), wx, a2);
      a2 = fmaf(fmaxf((float)s2.y + qy, 0.f), wy, a2);
      a3 = fmaf(fmaxf((float)s3.x + qx, 0.f), wx, a3);
      a3 = fmaf(fmaxf((float)s3.y + qy, 0.f), wy, a3);
    }
#endif
    pe[hg][0][j] = a0; pe[hg][1][j] = a1;
    pe[hg][2][j] = a2; pe[hg][3][j] = a3;
  }
  __syncthreads();

  // ---- combine h-halves + bias + leaky + mask ----
  {
    const float b2v = b2[0];
    #pragma unroll
    for (int r = 0; r < 2; ++r) {
      int idx = t + 1024 * r;               // 2048 cells of [ti][j]
      int ti = idx >> 9, j2 = idx & 511;
      float e = pe[0][ti][j2] + pe[1][ti][j2] + b2v;
      e = e > 0.f ? e : 0.04f * e;
      int av = adj[(b * NN + i0 + ti) * NN + j2];
      e_l[ti][j2] = (av > 0) ? e : -9.0e15f;
    }
  }
  __syncthreads();

  // ---- softmax: wave = (ti = wv>>2, j-quarter = wv&3), 2 vals/lane ----
  {
    const int ti = wv >> 2, qtr = wv & 3;
    float2 v = *(float2*)&e_l[ti][qtr * 128 + 2 * ln];
    float m = fmaxf(v.x, v.y);
    #pragma unroll
    for (int off = 32; off > 0; off >>= 1) m = fmaxf(m, __shfl_xor(m, off, 64));
    if (ln == 0) red_m[ti][qtr] = m;
    __syncthreads();
    m = fmaxf(fmaxf(red_m[ti][0], red_m[ti][1]), fmaxf(red_m[ti][2], red_m[ti][3]));
    v.x = __expf(v.x - m); v.y = __expf(v.y - m);
    float zs = v.x + v.y;
    #pragma unroll
    for (int off = 32; off > 0; off >>= 1) zs += __shfl_xor(zs, off, 64);
    if (ln == 0) red_s[ti][qtr] = zs;
    __syncthreads();
    float inv = 1.f / ((red_s[ti][0] + red_s[ti][1]) + (red_s[ti][2] + red_s[ti][3]));
    v.x *= inv; v.y *= inv;
    *(float2*)&e_l[ti][qtr * 128 + 2 * ln] = v;
  }
  __syncthreads();

  // attention[0,0,:] extra output
  if (blk == 0 && t < NN) out[BB * NN * FF + t] = e_l[0][t];

  // ---- next_h: wave wv owns 32 j-rows (x read once per block); lane = f-pair ----
  {
    const int jb = wv * 32;
    const int f2 = 2 * ln;
    v2f acc[TI];
    #pragma unroll
    for (int ti = 0; ti < TI; ++ti) acc[ti] = (v2f){0.f, 0.f};

    #pragma unroll 2
    for (int g = 0; g < 8; ++g) {
      const int j0 = jb + g * 4;
      float4 aa[TI];
      #pragma unroll
      for (int ti = 0; ti < TI; ++ti) aa[ti] = *(float4*)&e_l[ti][j0];  // broadcast b128
      #pragma unroll
      for (int k = 0; k < 4; ++k) {
        v2f x2 = *(const v2f*)(x + (b * NN + j0 + k) * FF + f2);        // coalesced 512B
        #pragma unroll
        for (int ti = 0; ti < TI; ++ti) {
          float w = (k == 0) ? aa[ti].x : (k == 1) ? aa[ti].y : (k == 2) ? aa[ti].z : aa[ti].w;
          acc[ti] = __builtin_elementwise_fma(splat2(w), x2, acc[ti]);
        }
      }
    }
    #pragma unroll
    for (int ti = 0; ti < TI; ++ti) *(v2f*)&part_l[wv][ti][f2] = acc[ti];
  }
  __syncthreads();
  if (t < TI * FF) {                         // 512 cells
    const int ti = t >> 7, f = t & 127;
    float r = 0.f;
    #pragma unroll
    for (int w = 0; w < 16; ++w) r += part_l[w][ti][f];
    out[(b * NN + i0 + ti) * FF + f] = r;
  }
}

extern "C" void kernel_launch(void* const* d_in, const int* in_sizes, int n_in,
                              void* d_out, int out_size, void* d_ws, size_t ws_size,
                              hipStream_t stream) {
  const float* x   = (const float*)d_in[0];
  const float* w1  = (const float*)d_in[1];
  const float* b1  = (const float*)d_in[2];
  const float* w2  = (const float*)d_in[3];
  const float* b2  = (const float*)d_in[4];
  const int*   adj = (const int*)  d_in[5];
  float* out = (float*)d_out;

  u32* s16  = (u32*)d_ws;                   // [1024][128] u32 (f16 h-pairs) = 512 KB
  u32* q16  = s16 + BB * NN * (HH / 2);     // [128][1024] u32 = 512 KB
  u32* w216 = q16 + (HH / 2) * (BB * NN);   // [128] u32

  dim3 g1(BB * NN / 16, (2 * HH) / 64);     // (64, 8) = 512 blocks
  k1_pq  <<<g1, 256, 0, stream>>>(x, w1, b1, w2, s16, q16, w216);
  k2_attn<<<BB * NN / TI, 1024, 0, stream>>>(s16, q16, w216, x, b2, adj, out);
}